// Round 6
// baseline (1101.028 us; speedup 1.0000x reference)
//
#include <hip/hip_runtime.h>

#define LNUM 4
#define DMODEL 1024
#define NHEAD 16
#define FDIM 4096
#define BATCH 4
#define SEQ 1024
#define HDIM 64
#define KBAND 8
#define MROWS (BATCH * SEQ)

typedef __attribute__((ext_vector_type(8))) __bf16 bf16x8;
typedef __attribute__((ext_vector_type(4))) float f32x4;
typedef __attribute__((ext_vector_type(8))) unsigned short u16x8;

__device__ __forceinline__ unsigned short f2bf(float f) {
  unsigned int u = __builtin_bit_cast(unsigned int, f);
  u = u + 0x7fffu + ((u >> 16) & 1u);
  return (unsigned short)(u >> 16);
}
__device__ __forceinline__ float bf2f(unsigned short h) {
  unsigned int u = ((unsigned int)h) << 16;
  return __builtin_bit_cast(float, u);
}

#define GLOAD16(gp, lp)                                                        \
  __builtin_amdgcn_global_load_lds(                                            \
      (const __attribute__((address_space(1))) void*)(gp),                     \
      (__attribute__((address_space(3))) void*)(lp), 16, 0, 0)

// ---------------- fp32 -> bf16 conversion -----------------------------------
__global__ __launch_bounds__(256) void cvt_bf16(const float* __restrict__ in,
                                                unsigned short* __restrict__ out,
                                                long n) {
  long i = ((long)blockIdx.x * 256 + threadIdx.x) * 4;
  if (i + 3 < n) {
    float4 v = *reinterpret_cast<const float4*>(in + i);
    ushort4 o;
    o.x = f2bf(v.x);
    o.y = f2bf(v.y);
    o.z = f2bf(v.z);
    o.w = f2bf(v.w);
    *reinterpret_cast<ushort4*>(out + i) = o;
  }
}

// ---------------- 256x256 8-phase bf16 GEMM, C = A * W^T + bias -------------
// A: [M,K] bf16 rm. W: [N,K] bf16 rm. 512 thr = 8 waves (2m x 4n).
// BK=64, LDS 128KB double-buffer, per-wave out 128x64 (acc 2x2x4x2 f32x4).
// T2 swizzle (conflict-free, verified R5: SQ_LDS_BANK_CONFLICT 9.4M -> 0):
//   (row,col) stored at row*64 + (col ^ ((row&7)<<3)); write side linear
//   LDS + pre-swizzled global source col; read side same XOR.
// Counted vmcnt(6) at phases 3/7 only (T4); setprio around MFMA (T5).
// NO sched_barrier(0): m141 measured order-pinning as a 42% regression;
//   template (gemm_256sq_8phase) has none. Compiler-visible ds_reads carry
//   their own lgkmcnt deps, so MFMA ordering stays correct (rule #18 applies
//   only to inline-asm ds_read, which we don't use).
// Epilogue: LDS-transpose (wave-private slice, no barrier) -> 2x dwordx4
//   coalesced stores per lane per set; exact-width writes (no 32B partials).
// blockIdx.z = K-split (range [z*Ks,(z+1)*Ks)).
// EPI: 0 = bf16 (+bias), 1 = bf16 (+bias, exact gelu),
//      2 = bf16 PARTIAL slab per z (bias only z==0).
#define BAR_MID()                                                              \
  __builtin_amdgcn_s_barrier();                                                \
  asm volatile("s_waitcnt lgkmcnt(0)" ::: "memory")

#define BAR_END() __builtin_amdgcn_s_barrier()

template <int EPI>
__global__ __launch_bounds__(512, 2) void gemm256(const unsigned short* __restrict__ A,
                                                  const unsigned short* __restrict__ W,
                                                  const float* __restrict__ bias,
                                                  unsigned short* __restrict__ Cout,
                                                  int Ndim, int Kdim, int Ks) {
  __shared__ unsigned short As[2][16384];  // [buf][256r x 64k, col-swizzled]
  __shared__ unsigned short Bs[2][16384];
  const int tid = threadIdx.x;
  const int wave = tid >> 6;
  const int lane = tid & 63;
  const int wm = wave >> 2;  // 0..1
  const int wn = wave & 3;   // 0..3

  // bijective XCD chunked swizzle (m204); bm-fastest in chunk keeps each
  // XCD's B (weight) slab L2-resident while A streams.
  const int gx = gridDim.x, gy = gridDim.y;
  const int nwg = gx * gy;
  const int lin = blockIdx.x + blockIdx.y * gx;
  const int q8 = nwg >> 3, r8 = nwg & 7;
  const int xcd = lin & 7, cidx = lin >> 3;
  const int cbase = (xcd < r8) ? xcd * (q8 + 1) : r8 * (q8 + 1) + (xcd - r8) * q8;
  const int swz = cbase + cidx;
  const int bm0 = (swz % gy) * 256;
  const int bn0 = (swz / gy) * 256;
  const int kz0 = blockIdx.z * Ks;

  // staging: half-tile = 128r x 64k = 16KB = 512thr x 16B x 2 instrs
  const int r0 = tid >> 3;                               // 0..63
  const int c0 = (((tid & 7) ^ ((tid >> 3) & 7)) << 3);  // pre-swizzled col
  const size_t rowstep = (size_t)64 * Kdim;

#define STAGEH(MAT, rowg, buf, LDSARR, h, kt)                                  \
  do {                                                                         \
    const unsigned short* g = MAT + (size_t)((rowg) + (h) * 128 + r0) * Kdim + \
                              kz0 + (kt) * 64 + c0;                            \
    char* lb = (char*)&LDSARR[buf][0] + (h) * 16384 + wave * 1024;             \
    GLOAD16(g, lb);                                                            \
    GLOAD16(g + rowstep, lb + 8192);                                           \
  } while (0)

  const int fr = lane & 15;
  const int kc = (lane >> 4) * 8;
  const int fsw = (fr & 7) << 3;  // read-side XOR (row&7 == fr&7)
  bf16x8 A0[2][4], A1[2][4], Bv[2][2];
  f32x4 acc[2][2][4][2] = {};

#define RD_A(SET, buf, rh)                                                     \
  _Pragma("unroll") for (int ks = 0; ks < 2; ++ks)                             \
      _Pragma("unroll") for (int fi = 0; fi < 4; ++fi)                         \
      SET[ks][fi] = *reinterpret_cast<const bf16x8*>(                          \
          &As[buf][(wm * 128 + (rh) * 64 + fi * 16 + fr) * 64 +                \
                   ((ks * 32 + kc) ^ fsw)]);

#define RD_B(buf, ch)                                                          \
  _Pragma("unroll") for (int ks = 0; ks < 2; ++ks)                             \
      _Pragma("unroll") for (int fj = 0; fj < 2; ++fj)                         \
      Bv[ks][fj] = *reinterpret_cast<const bf16x8*>(                           \
          &Bs[buf][(wn * 64 + (ch) * 32 + fj * 16 + fr) * 64 +                 \
                   ((ks * 32 + kc) ^ fsw)]);

#define MFMA_Q(rh, ch, ASET)                                                   \
  __builtin_amdgcn_s_setprio(1);                                               \
  _Pragma("unroll") for (int ks = 0; ks < 2; ++ks)                             \
      _Pragma("unroll") for (int fi = 0; fi < 4; ++fi)                         \
      _Pragma("unroll") for (int fj = 0; fj < 2; ++fj)                         \
      acc[rh][ch][fi][fj] = __builtin_amdgcn_mfma_f32_16x16x32_bf16(           \
          ASET[ks][fi], Bv[ks][fj], acc[rh][ch][fi][fj], 0, 0, 0);             \
  __builtin_amdgcn_s_setprio(0)

  const int nt = Ks >> 6;  // K-tiles; even, >= 2
  // prologue: tile0 (4 halves)->buf0, tile1 (Alo,Ahi,Blo)->buf1  [14 loads]
  STAGEH(A, bm0, 0, As, 0, 0);
  STAGEH(A, bm0, 0, As, 1, 0);
  STAGEH(W, bn0, 0, Bs, 0, 0);
  STAGEH(W, bn0, 0, Bs, 1, 0);
  STAGEH(A, bm0, 1, As, 0, 1);
  STAGEH(A, bm0, 1, As, 1, 1);
  STAGEH(W, bn0, 1, Bs, 0, 1);
  asm volatile("s_waitcnt vmcnt(6)" ::: "memory");  // tile0 fully landed
  BAR_END();

  const int npair = nt >> 1;
  for (int i = 0; i < npair; ++i) {
    const int t1 = 2 * i + 1, t2 = 2 * i + 2, t3 = 2 * i + 3;
    const bool pf = (t2 < nt);
    // ---- phases 0-3: compute tile 2i (buf0) ----
    RD_A(A0, 0, 0);
    RD_B(0, 0);
    STAGEH(W, bn0, 1, Bs, 1, t1);  // B-hi(t1)->buf1 (region idle since ph6 prev)
    BAR_MID();
    MFMA_Q(0, 0, A0);
    BAR_END();

    RD_A(A1, 0, 1);
    BAR_MID();
    MFMA_Q(1, 0, A1);
    BAR_END();

    RD_B(0, 1);
    if (pf) STAGEH(A, bm0, 0, As, 0, t2);  // A-lo read drained ph1
    BAR_MID();
    MFMA_Q(1, 1, A1);
    BAR_END();

    if (pf) {
      STAGEH(A, bm0, 0, As, 1, t2);
      STAGEH(W, bn0, 0, Bs, 0, t2);  // B-lo read drained ph2
    }
    BAR_MID();
    MFMA_Q(0, 1, A0);
    if (pf)
      asm volatile("s_waitcnt vmcnt(6)" ::: "memory");  // tile t1 landed
    else
      asm volatile("s_waitcnt vmcnt(0)" ::: "memory");
    BAR_END();

    // ---- phases 4-7: compute tile 2i+1 (buf1) ----
    RD_A(A0, 1, 0);
    RD_B(1, 0);
    if (pf) STAGEH(W, bn0, 0, Bs, 1, t2);  // B-hi(t2)->buf0
    BAR_MID();
    MFMA_Q(0, 0, A0);
    BAR_END();

    RD_A(A1, 1, 1);
    BAR_MID();
    MFMA_Q(1, 0, A1);
    BAR_END();

    RD_B(1, 1);
    if (pf) STAGEH(A, bm0, 1, As, 0, t3);
    BAR_MID();
    MFMA_Q(1, 1, A1);
    BAR_END();

    if (pf) {
      STAGEH(A, bm0, 1, As, 1, t3);
      STAGEH(W, bn0, 1, Bs, 0, t3);
    }
    BAR_MID();
    MFMA_Q(0, 1, A0);
    if (pf) asm volatile("s_waitcnt vmcnt(6)" ::: "memory");  // tile t2 landed
    BAR_END();
  }

#undef STAGEH
#undef RD_A
#undef RD_B
#undef MFMA_Q

  // ---- epilogue: LDS-transpose, wave-private (no barriers needed) ----
  // C/D layout col=lane&15, row=(lane>>4)*4+reg (m89/m91). Per set
  // (rh,ch,fj): 64 rows x 16 cols staged to a 4KB wave slice; lane L then
  // owns global row base+L and stores 16 bf16 as 2x dwordx4.
  const int rr = (lane >> 4) * 4;
  const int cc = lane & 15;
  const bool addb = (EPI != 2) || (blockIdx.z == 0);
  unsigned short* outZ =
      Cout + (EPI == 2 ? (size_t)blockIdx.z * ((size_t)gy * 256) * Ndim : 0);
  float* lt = (float*)&As[0][0] + wave * 1024;  // 4KB per wave, 8x4=32KB<64KB
#pragma unroll
  for (int s = 0; s < 8; ++s) {
    const int rh = s >> 2, ch = (s >> 1) & 1, fj = s & 1;
#pragma unroll
    for (int fi = 0; fi < 4; ++fi)
#pragma unroll
      for (int r = 0; r < 4; ++r)
        lt[(fi * 16 + rr + r) * 16 + cc] = acc[rh][ch][fi][fj][r];
    asm volatile("s_waitcnt lgkmcnt(0)" ::: "memory");  // wave-internal RAW
    const int n0 = bn0 + wn * 64 + ch * 32 + fj * 16;
    const int m = bm0 + wm * 128 + rh * 64 + lane;
    u16x8 o0, o1;
#pragma unroll
    for (int j = 0; j < 8; ++j) {
      float v = lt[lane * 16 + j] + (addb ? bias[n0 + j] : 0.0f);
      if (EPI == 1) v = 0.5f * v * (1.0f + erff(v * 0.70710678118654752f));
      o0[j] = f2bf(v);
    }
#pragma unroll
    for (int j = 0; j < 8; ++j) {
      float v = lt[lane * 16 + 8 + j] + (addb ? bias[n0 + 8 + j] : 0.0f);
      if (EPI == 1) v = 0.5f * v * (1.0f + erff(v * 0.70710678118654752f));
      o1[j] = f2bf(v);
    }
    unsigned short* dst = outZ + (size_t)m * Ndim + n0;
    *reinterpret_cast<u16x8*>(dst) = o0;
    *reinterpret_cast<u16x8*>(dst + 8) = o1;
  }
}

// ---------------- banded attention: one wave per (b,h,q), lane = d ----------
__global__ __launch_bounds__(256) void attn_band(const unsigned short* __restrict__ qkv,
                                                 unsigned short* __restrict__ outp) {
  const int gw = blockIdx.x * 4 + (threadIdx.x >> 6);
  const int lane = threadIdx.x & 63;
  const int q = gw & (SEQ - 1);
  const int bh = gw >> 10;
  const int h = bh & (NHEAD - 1);
  const int b = bh >> 4;
  const size_t row0 = (size_t)(b * SEQ + q);
  const size_t stride = 3 * DMODEL;
  const float qv = bf2f(qkv[row0 * stride + h * HDIM + lane]);

  float sc[KBAND];
  float mx = -1e30f;
#pragma unroll
  for (int jj = 0; jj < KBAND; ++jj) {
    const int j = q + jj;
    const int jc = (j < SEQ) ? j : (SEQ - 1);
    float kv = bf2f(qkv[(size_t)(b * SEQ + jc) * stride + DMODEL + h * HDIM + lane]);
    float p = qv * kv;
#pragma unroll
    for (int m = 32; m; m >>= 1) p += __shfl_xor(p, m);
    p *= 0.125f;
    p = (j < SEQ) ? p : -1e30f;
    sc[jj] = p;
    mx = fmaxf(mx, p);
  }
  float denom = 0.f;
  float ov = 0.f;
#pragma unroll
  for (int jj = 0; jj < KBAND; ++jj) {
    const int j = q + jj;
    const int jc = (j < SEQ) ? j : (SEQ - 1);
    float p = __expf(sc[jj] - mx);
    p = (j < SEQ) ? p : 0.f;
    denom += p;
    ov += p * bf2f(qkv[(size_t)(b * SEQ + jc) * stride + 2 * DMODEL + h * HDIM + lane]);
  }
  ov /= denom;
  outp[row0 * DMODEL + h * HDIM + lane] = f2bf(ov);
}

// ---------------- residual + 4-way bf16 split-K reduce + LayerNorm ----------
__global__ __launch_bounds__(256) void add_ln4(const float* __restrict__ resid,
                                               const unsigned short* __restrict__ part,
                                               const float* __restrict__ gw,
                                               const float* __restrict__ gb,
                                               float* __restrict__ xf,
                                               unsigned short* __restrict__ xb) {
  const int row = blockIdx.x;
  const int tid = threadIdx.x;
  const size_t slab = (size_t)MROWS * DMODEL;
  const float* rp = resid + (size_t)row * DMODEL;
  const unsigned short* pp = part + (size_t)row * DMODEL;
  float v[4];
  float s = 0.f, s2 = 0.f;
#pragma unroll
  for (int i = 0; i < 4; ++i) {
    const int idx = tid + i * 256;
    float a = rp[idx];
#pragma unroll
    for (int z = 0; z < 4; ++z) a += bf2f(pp[z * slab + idx]);
    v[i] = a;
    s += a;
    s2 += a * a;
  }
#pragma unroll
  for (int m = 32; m; m >>= 1) {
    s += __shfl_xor(s, m);
    s2 += __shfl_xor(s2, m);
  }
  __shared__ float wsm[8];
  const int wave = tid >> 6, lane = tid & 63;
  if (lane == 0) {
    wsm[wave] = s;
    wsm[4 + wave] = s2;
  }
  __syncthreads();
  s = wsm[0] + wsm[1] + wsm[2] + wsm[3];
  s2 = wsm[4] + wsm[5] + wsm[6] + wsm[7];
  const float mean = s * (1.f / DMODEL);
  const float var = s2 * (1.f / DMODEL) - mean * mean;
  const float rstd = rsqrtf(var + 1e-5f);
#pragma unroll
  for (int i = 0; i < 4; ++i) {
    const int idx = tid + i * 256;
    const float y = (v[i] - mean) * rstd * gw[idx] + gb[idx];
    xf[(size_t)row * DMODEL + idx] = y;
    xb[(size_t)row * DMODEL + idx] = f2bf(y);
  }
}

extern "C" void kernel_launch(void* const* d_in, const int* in_sizes, int n_in,
                              void* d_out, int out_size, void* d_ws, size_t ws_size,
                              hipStream_t stream) {
  const float* src  = (const float*)d_in[0];
  const float* Wqkv = (const float*)d_in[1];
  const float* bqkv = (const float*)d_in[2];
  const float* Wo   = (const float*)d_in[3];
  const float* bo   = (const float*)d_in[4];
  const float* W1   = (const float*)d_in[5];
  const float* b1   = (const float*)d_in[6];
  const float* W2   = (const float*)d_in[7];
  const float* b2   = (const float*)d_in[8];
  const float* ln1w = (const float*)d_in[9];
  const float* ln1b = (const float*)d_in[10];
  const float* ln2w = (const float*)d_in[11];
  const float* ln2b = (const float*)d_in[12];
  float* out = (float*)d_out;

  // workspace carve-up (~193 MB of 209.7 MB)
  char* p = (char*)d_ws;
  unsigned short* wqkv_b = (unsigned short*)p; p += (size_t)LNUM * 3072 * 1024 * 2;
  unsigned short* wo_b   = (unsigned short*)p; p += (size_t)LNUM * 1024 * 1024 * 2;
  unsigned short* w1_b   = (unsigned short*)p; p += (size_t)LNUM * 4096 * 1024 * 2;
  unsigned short* w2_b   = (unsigned short*)p; p += (size_t)LNUM * 1024 * 4096 * 2;
  float*          xf     = (float*)p;          p += (size_t)MROWS * DMODEL * 4;
  unsigned short* xb     = (unsigned short*)p; p += (size_t)MROWS * DMODEL * 2;
  // region R: [qkvb 24MB | aob 8MB] aliased by [hb 32MB], then part 4x8MB bf16
  char* R = p;
  unsigned short* qkvb = (unsigned short*)R;
  unsigned short* aob  = (unsigned short*)(R + (size_t)MROWS * 3 * DMODEL * 2);
  unsigned short* hb   = (unsigned short*)R;
  unsigned short* part = (unsigned short*)(R + (size_t)MROWS * 4096 * 2);
  p = R + (size_t)MROWS * 4096 * 2 + (size_t)4 * MROWS * DMODEL * 2;
  if (ws_size < (size_t)(p - (char*)d_ws)) return;

  cvt_bf16<<<(long)LNUM * 3072 * 1024 / 1024, 256, 0, stream>>>(Wqkv, wqkv_b, (long)LNUM * 3072 * 1024);
  cvt_bf16<<<(long)LNUM * 1024 * 1024 / 1024, 256, 0, stream>>>(Wo, wo_b, (long)LNUM * 1024 * 1024);
  cvt_bf16<<<(long)LNUM * 4096 * 1024 / 1024, 256, 0, stream>>>(W1, w1_b, (long)LNUM * 4096 * 1024);
  cvt_bf16<<<(long)LNUM * 1024 * 4096 / 1024, 256, 0, stream>>>(W2, w2_b, (long)LNUM * 1024 * 4096);
  cvt_bf16<<<(long)MROWS * DMODEL / 1024, 256, 0, stream>>>(src, xb, (long)MROWS * DMODEL);

  for (int l = 0; l < LNUM; ++l) {
    // QKV: [4096,1024] x [3072,1024]^T -> bf16 [4096,3072]
    gemm256<0><<<dim3(3072 / 256, MROWS / 256, 1), 512, 0, stream>>>(
        xb, wqkv_b + (size_t)l * 3072 * 1024, bqkv + l * 3072, qkvb, 3072, 1024, 1024);
    attn_band<<<(BATCH * NHEAD * SEQ) / 4, 256, 0, stream>>>(qkvb, aob);
    // Wo: split-K=4 (Ks=256) -> bf16 partial slabs
    gemm256<2><<<dim3(1024 / 256, MROWS / 256, 4), 512, 0, stream>>>(
        aob, wo_b + (size_t)l * 1024 * 1024, bo + l * 1024, part, 1024, 1024, 256);
    add_ln4<<<MROWS, 256, 0, stream>>>(l == 0 ? src : xf, part,
                                       ln1w + l * DMODEL, ln1b + l * DMODEL, xf, xb);
    // W1 + gelu: [4096,1024] x [4096,1024]^T -> bf16 [4096,4096]
    gemm256<1><<<dim3(FDIM / 256, MROWS / 256, 1), 512, 0, stream>>>(
        xb, w1_b + (size_t)l * 4096 * 1024, b1 + l * FDIM, hb, FDIM, 1024, 1024);
    // W2: split-K=4 (Ks=1024) -> bf16 partial slabs
    gemm256<2><<<dim3(1024 / 256, MROWS / 256, 4), 512, 0, stream>>>(
        hb, w2_b + (size_t)l * 1024 * 4096, b2 + l * 1024, part, 1024, 4096, 1024);
    float* dst = (l == LNUM - 1) ? out : xf;
    add_ln4<<<MROWS, 256, 0, stream>>>(xf, part,
                                       ln2w + l * DMODEL, ln2b + l * DMODEL, dst, xb);
  }
}

// Round 7
// 952.043 us; speedup vs baseline: 1.1565x; 1.1565x over previous
//
#include <hip/hip_runtime.h>

#define LNUM 4
#define DMODEL 1024
#define NHEAD 16
#define FDIM 4096
#define BATCH 4
#define SEQ 1024
#define HDIM 64
#define KBAND 8
#define MROWS (BATCH * SEQ)

typedef __attribute__((ext_vector_type(8))) __bf16 bf16x8;
typedef __attribute__((ext_vector_type(4))) float f32x4;

__device__ __forceinline__ unsigned short f2bf(float f) {
  unsigned int u = __builtin_bit_cast(unsigned int, f);
  u = u + 0x7fffu + ((u >> 16) & 1u);
  return (unsigned short)(u >> 16);
}
__device__ __forceinline__ float bf2f(unsigned short h) {
  unsigned int u = ((unsigned int)h) << 16;
  return __builtin_bit_cast(float, u);
}

#define GLOAD16(gp, lp)                                                        \
  __builtin_amdgcn_global_load_lds(                                            \
      (const __attribute__((address_space(1))) void*)(gp),                     \
      (__attribute__((address_space(3))) void*)(lp), 16, 0, 0)

// ---------------- fp32 -> bf16 conversion -----------------------------------
__global__ __launch_bounds__(256) void cvt_bf16(const float* __restrict__ in,
                                                unsigned short* __restrict__ out,
                                                long n) {
  long i = ((long)blockIdx.x * 256 + threadIdx.x) * 4;
  if (i + 3 < n) {
    float4 v = *reinterpret_cast<const float4*>(in + i);
    ushort4 o;
    o.x = f2bf(v.x);
    o.y = f2bf(v.y);
    o.z = f2bf(v.z);
    o.w = f2bf(v.w);
    *reinterpret_cast<ushort4*>(out + i) = o;
  }
}

// ---------------- 256x256 2-phase bf16 GEMM, C = A * W^T + bias -------------
// A: [M,K] bf16 rm. W: [N,K] bf16 rm. 512 thr = 8 waves (2m x 4n).
// BK=64, LDS 128KB double-buffer, per-wave out 128x64 (acc 2x2x4x2 f32x4).
// T3-minimum 2-phase (guide recipe; m248/m230 measured 655-682 TF @256^2
// K=1024, beating our 8-phase port's 460):
//   loop: STAGE(next tile, 8 gload_lds) -> 24 ds_read (all frags) ->
//         64 MFMA -> __syncthreads (one vmcnt0+lgkm0+barrier per K-TILE).
//   Stage issued BEFORE compute so ~1400 cyc of ds_read+MFMA covers the
//   load latency; only ONE barrier per tile (vs 16 in the 8-phase port).
// T2 swizzle kept (verified 0 conflicts in R5): (row,col) stored at
//   row*64 + (col ^ ((row&7)<<3)); linear LDS dest + pre-swizzled global
//   source col; same XOR on reads. No setprio (m190: null at 2-phase).
// blockIdx.z = K-split (range [z*Ks,(z+1)*Ks)).
// EPI: 0 = bf16 (+bias), 1 = bf16 (+bias, exact gelu),
//      2 = bf16 PARTIAL slab per z (bias only z==0).
template <int EPI>
__global__ __launch_bounds__(512, 2) void gemm256(const unsigned short* __restrict__ A,
                                                  const unsigned short* __restrict__ W,
                                                  const float* __restrict__ bias,
                                                  unsigned short* __restrict__ Cout,
                                                  int Ndim, int Kdim, int Ks) {
  __shared__ unsigned short As[2][16384];  // [buf][256r x 64k, col-swizzled]
  __shared__ unsigned short Bs[2][16384];
  const int tid = threadIdx.x;
  const int wave = tid >> 6;
  const int lane = tid & 63;
  const int wm = wave >> 2;  // 0..1
  const int wn = wave & 3;   // 0..3

  // bijective XCD chunked swizzle (m204); bm-fastest in chunk keeps each
  // XCD's B (weight) slab L2-resident while A streams.
  const int gx = gridDim.x, gy = gridDim.y;
  const int nwg = gx * gy;
  const int lin = blockIdx.x + blockIdx.y * gx;
  const int q8 = nwg >> 3, r8 = nwg & 7;
  const int xcd = lin & 7, cidx = lin >> 3;
  const int cbase = (xcd < r8) ? xcd * (q8 + 1) : r8 * (q8 + 1) + (xcd - r8) * q8;
  const int swz = cbase + cidx;
  const int bm0 = (swz % gy) * 256;
  const int bn0 = (swz / gy) * 256;
  const int kz0 = blockIdx.z * Ks;

  // staging: half-tile = 128r x 64k = 16KB = 512thr x 16B x 2 instrs
  const int r0 = tid >> 3;                               // 0..63
  const int c0 = (((tid & 7) ^ ((tid >> 3) & 7)) << 3);  // pre-swizzled col
  const size_t rowstep = (size_t)64 * Kdim;

#define STAGEH(MAT, rowg, buf, LDSARR, h, kt)                                  \
  do {                                                                         \
    const unsigned short* g = MAT + (size_t)((rowg) + (h) * 128 + r0) * Kdim + \
                              kz0 + (kt) * 64 + c0;                            \
    char* lb = (char*)&LDSARR[buf][0] + (h) * 16384 + wave * 1024;             \
    GLOAD16(g, lb);                                                            \
    GLOAD16(g + rowstep, lb + 8192);                                           \
  } while (0)

#define STAGE_TILE(buf, kt)                                                    \
  do {                                                                         \
    STAGEH(A, bm0, buf, As, 0, kt);                                            \
    STAGEH(A, bm0, buf, As, 1, kt);                                            \
    STAGEH(W, bn0, buf, Bs, 0, kt);                                            \
    STAGEH(W, bn0, buf, Bs, 1, kt);                                            \
  } while (0)

  const int fr = lane & 15;
  const int kc = (lane >> 4) * 8;
  const int fsw = (fr & 7) << 3;  // read-side XOR (row&7 == fr&7)
  f32x4 acc[2][2][4][2] = {};

  const int nt = Ks >> 6;  // K-tiles
  STAGE_TILE(0, 0);
  asm volatile("s_waitcnt vmcnt(0)" ::: "memory");
  __builtin_amdgcn_s_barrier();

  for (int t = 0; t < nt; ++t) {
    const int cur = t & 1;
    if (t + 1 < nt) STAGE_TILE(cur ^ 1, t + 1);  // issue loads FIRST (overlap)

    bf16x8 Af[2][2][4], Bf[2][2][2];
#pragma unroll
    for (int rh = 0; rh < 2; ++rh)
#pragma unroll
      for (int ks = 0; ks < 2; ++ks)
#pragma unroll
        for (int fi = 0; fi < 4; ++fi)
          Af[rh][ks][fi] = *reinterpret_cast<const bf16x8*>(
              &As[cur][(wm * 128 + rh * 64 + fi * 16 + fr) * 64 +
                       ((ks * 32 + kc) ^ fsw)]);
#pragma unroll
    for (int ch = 0; ch < 2; ++ch)
#pragma unroll
      for (int ks = 0; ks < 2; ++ks)
#pragma unroll
        for (int fj = 0; fj < 2; ++fj)
          Bf[ch][ks][fj] = *reinterpret_cast<const bf16x8*>(
              &Bs[cur][(wn * 64 + ch * 32 + fj * 16 + fr) * 64 +
                       ((ks * 32 + kc) ^ fsw)]);

#pragma unroll
    for (int rh = 0; rh < 2; ++rh)
#pragma unroll
      for (int ch = 0; ch < 2; ++ch)
#pragma unroll
        for (int ks = 0; ks < 2; ++ks)
#pragma unroll
          for (int fi = 0; fi < 4; ++fi)
#pragma unroll
            for (int fj = 0; fj < 2; ++fj)
              acc[rh][ch][fi][fj] = __builtin_amdgcn_mfma_f32_16x16x32_bf16(
                  Af[rh][ks][fi], Bf[ch][ks][fj], acc[rh][ch][fi][fj], 0, 0, 0);

    __syncthreads();  // one vmcnt(0)+lgkmcnt(0)+barrier per K-tile
  }

#undef STAGEH
#undef STAGE_TILE

  // epilogue (R5 config): C/D layout col=lane&15, row=(lane>>4)*4+reg
  const int rr = (lane >> 4) * 4;
  const int cc = lane & 15;
  const bool addb = (EPI != 2) || (blockIdx.z == 0);
  unsigned short* outZ =
      Cout + (EPI == 2 ? (size_t)blockIdx.z * ((size_t)gy * 256) * Ndim : 0);
#pragma unroll
  for (int rh = 0; rh < 2; ++rh)
#pragma unroll
    for (int ch = 0; ch < 2; ++ch)
#pragma unroll
      for (int fj = 0; fj < 2; ++fj) {
        const int n = bn0 + wn * 64 + ch * 32 + fj * 16 + cc;
        const float bv = addb ? bias[n] : 0.0f;
#pragma unroll
        for (int fi = 0; fi < 4; ++fi)
#pragma unroll
          for (int r = 0; r < 4; ++r) {
            const int m = bm0 + wm * 128 + rh * 64 + fi * 16 + rr + r;
            float v = acc[rh][ch][fi][fj][r] + bv;
            if (EPI == 1) v = 0.5f * v * (1.0f + erff(v * 0.70710678118654752f));
            outZ[(size_t)m * Ndim + n] = f2bf(v);
          }
      }
}

// ---------------- banded attention: one wave per (b,h,q), lane = d ----------
__global__ __launch_bounds__(256) void attn_band(const unsigned short* __restrict__ qkv,
                                                 unsigned short* __restrict__ outp) {
  const int gw = blockIdx.x * 4 + (threadIdx.x >> 6);
  const int lane = threadIdx.x & 63;
  const int q = gw & (SEQ - 1);
  const int bh = gw >> 10;
  const int h = bh & (NHEAD - 1);
  const int b = bh >> 4;
  const size_t row0 = (size_t)(b * SEQ + q);
  const size_t stride = 3 * DMODEL;
  const float qv = bf2f(qkv[row0 * stride + h * HDIM + lane]);

  float sc[KBAND];
  float mx = -1e30f;
#pragma unroll
  for (int jj = 0; jj < KBAND; ++jj) {
    const int j = q + jj;
    const int jc = (j < SEQ) ? j : (SEQ - 1);
    float kv = bf2f(qkv[(size_t)(b * SEQ + jc) * stride + DMODEL + h * HDIM + lane]);
    float p = qv * kv;
#pragma unroll
    for (int m = 32; m; m >>= 1) p += __shfl_xor(p, m);
    p *= 0.125f;
    p = (j < SEQ) ? p : -1e30f;
    sc[jj] = p;
    mx = fmaxf(mx, p);
  }
  float denom = 0.f;
  float ov = 0.f;
#pragma unroll
  for (int jj = 0; jj < KBAND; ++jj) {
    const int j = q + jj;
    const int jc = (j < SEQ) ? j : (SEQ - 1);
    float p = __expf(sc[jj] - mx);
    p = (j < SEQ) ? p : 0.f;
    denom += p;
    ov += p * bf2f(qkv[(size_t)(b * SEQ + jc) * stride + 2 * DMODEL + h * HDIM + lane]);
  }
  ov /= denom;
  outp[row0 * DMODEL + h * HDIM + lane] = f2bf(ov);
}

// ---------------- residual + 4-way bf16 split-K reduce + LayerNorm ----------
__global__ __launch_bounds__(256) void add_ln4(const float* __restrict__ resid,
                                               const unsigned short* __restrict__ part,
                                               const float* __restrict__ gw,
                                               const float* __restrict__ gb,
                                               float* __restrict__ xf,
                                               unsigned short* __restrict__ xb) {
  const int row = blockIdx.x;
  const int tid = threadIdx.x;
  const size_t slab = (size_t)MROWS * DMODEL;
  const float* rp = resid + (size_t)row * DMODEL;
  const unsigned short* pp = part + (size_t)row * DMODEL;
  float v[4];
  float s = 0.f, s2 = 0.f;
#pragma unroll
  for (int i = 0; i < 4; ++i) {
    const int idx = tid + i * 256;
    float a = rp[idx];
#pragma unroll
    for (int z = 0; z < 4; ++z) a += bf2f(pp[z * slab + idx]);
    v[i] = a;
    s += a;
    s2 += a * a;
  }
#pragma unroll
  for (int m = 32; m; m >>= 1) {
    s += __shfl_xor(s, m);
    s2 += __shfl_xor(s2, m);
  }
  __shared__ float wsm[8];
  const int wave = tid >> 6, lane = tid & 63;
  if (lane == 0) {
    wsm[wave] = s;
    wsm[4 + wave] = s2;
  }
  __syncthreads();
  s = wsm[0] + wsm[1] + wsm[2] + wsm[3];
  s2 = wsm[4] + wsm[5] + wsm[6] + wsm[7];
  const float mean = s * (1.f / DMODEL);
  const float var = s2 * (1.f / DMODEL) - mean * mean;
  const float rstd = rsqrtf(var + 1e-5f);
#pragma unroll
  for (int i = 0; i < 4; ++i) {
    const int idx = tid + i * 256;
    const float y = (v[i] - mean) * rstd * gw[idx] + gb[idx];
    xf[(size_t)row * DMODEL + idx] = y;
    xb[(size_t)row * DMODEL + idx] = f2bf(y);
  }
}

extern "C" void kernel_launch(void* const* d_in, const int* in_sizes, int n_in,
                              void* d_out, int out_size, void* d_ws, size_t ws_size,
                              hipStream_t stream) {
  const float* src  = (const float*)d_in[0];
  const float* Wqkv = (const float*)d_in[1];
  const float* bqkv = (const float*)d_in[2];
  const float* Wo   = (const float*)d_in[3];
  const float* bo   = (const float*)d_in[4];
  const float* W1   = (const float*)d_in[5];
  const float* b1   = (const float*)d_in[6];
  const float* W2   = (const float*)d_in[7];
  const float* b2   = (const float*)d_in[8];
  const float* ln1w = (const float*)d_in[9];
  const float* ln1b = (const float*)d_in[10];
  const float* ln2w = (const float*)d_in[11];
  const float* ln2b = (const float*)d_in[12];
  float* out = (float*)d_out;

  // workspace carve-up (~193 MB of 209.7 MB)
  char* p = (char*)d_ws;
  unsigned short* wqkv_b = (unsigned short*)p; p += (size_t)LNUM * 3072 * 1024 * 2;
  unsigned short* wo_b   = (unsigned short*)p; p += (size_t)LNUM * 1024 * 1024 * 2;
  unsigned short* w1_b   = (unsigned short*)p; p += (size_t)LNUM * 4096 * 1024 * 2;
  unsigned short* w2_b   = (unsigned short*)p; p += (size_t)LNUM * 1024 * 4096 * 2;
  float*          xf     = (float*)p;          p += (size_t)MROWS * DMODEL * 4;
  unsigned short* xb     = (unsigned short*)p; p += (size_t)MROWS * DMODEL * 2;
  // region R: [qkvb 24MB | aob 8MB] aliased by [hb 32MB], then part 4x8MB bf16
  char* R = p;
  unsigned short* qkvb = (unsigned short*)R;
  unsigned short* aob  = (unsigned short*)(R + (size_t)MROWS * 3 * DMODEL * 2);
  unsigned short* hb   = (unsigned short*)R;
  unsigned short* part = (unsigned short*)(R + (size_t)MROWS * 4096 * 2);
  p = R + (size_t)MROWS * 4096 * 2 + (size_t)4 * MROWS * DMODEL * 2;
  if (ws_size < (size_t)(p - (char*)d_ws)) return;

  cvt_bf16<<<(long)LNUM * 3072 * 1024 / 1024, 256, 0, stream>>>(Wqkv, wqkv_b, (long)LNUM * 3072 * 1024);
  cvt_bf16<<<(long)LNUM * 1024 * 1024 / 1024, 256, 0, stream>>>(Wo, wo_b, (long)LNUM * 1024 * 1024);
  cvt_bf16<<<(long)LNUM * 4096 * 1024 / 1024, 256, 0, stream>>>(W1, w1_b, (long)LNUM * 4096 * 1024);
  cvt_bf16<<<(long)LNUM * 1024 * 4096 / 1024, 256, 0, stream>>>(W2, w2_b, (long)LNUM * 1024 * 4096);
  cvt_bf16<<<(long)MROWS * DMODEL / 1024, 256, 0, stream>>>(src, xb, (long)MROWS * DMODEL);

  for (int l = 0; l < LNUM; ++l) {
    // QKV: [4096,1024] x [3072,1024]^T -> bf16 [4096,3072]
    gemm256<0><<<dim3(3072 / 256, MROWS / 256, 1), 512, 0, stream>>>(
        xb, wqkv_b + (size_t)l * 3072 * 1024, bqkv + l * 3072, qkvb, 3072, 1024, 1024);
    attn_band<<<(BATCH * NHEAD * SEQ) / 4, 256, 0, stream>>>(qkvb, aob);
    // Wo: split-K=4 (Ks=256) -> bf16 partial slabs
    gemm256<2><<<dim3(1024 / 256, MROWS / 256, 4), 512, 0, stream>>>(
        aob, wo_b + (size_t)l * 1024 * 1024, bo + l * 1024, part, 1024, 1024, 256);
    add_ln4<<<MROWS, 256, 0, stream>>>(l == 0 ? src : xf, part,
                                       ln1w + l * DMODEL, ln1b + l * DMODEL, xf, xb);
    // W1 + gelu: [4096,1024] x [4096,1024]^T -> bf16 [4096,4096]
    gemm256<1><<<dim3(FDIM / 256, MROWS / 256, 1), 512, 0, stream>>>(
        xb, w1_b + (size_t)l * 4096 * 1024, b1 + l * FDIM, hb, FDIM, 1024, 1024);
    // W2: split-K=4 (Ks=1024) -> bf16 partial slabs
    gemm256<2><<<dim3(1024 / 256, MROWS / 256, 4), 512, 0, stream>>>(
        hb, w2_b + (size_t)l * 1024 * 4096, b2 + l * 1024, part, 1024, 4096, 1024);
    float* dst = (l == LNUM - 1) ? out : xf;
    add_ln4<<<MROWS, 256, 0, stream>>>(xf, part,
                                       ln2w + l * DMODEL, ln2b + l * DMODEL, dst, xb);
  }
}